// Round 10
// baseline (310.290 us; speedup 1.0000x reference)
//
#include <hip/hip_runtime.h>
#include <hip/hip_bf16.h>

// Problem: B=32, L=256 -> 8192 tokens; DIN=320, DR=256, DH=512, E=8, top-2.
#define N_TOK   8192
#define DMODEL  256
#define NFEAT   8
#define DFEAT   64
#define DIN     320
#define DRTR    256
#define NE      8
#define DH      512
#define TE      32      // tokens per expert tile (2 m-tiles)
#define RTB     32      // tokens per router block
#define FIXCAP  128
#define FIXTHR  2e-3f

// d_out layout (floats): [stage_delta 8192*256][gate_weights 8192*8][gate_logits 8192*8]
#define OUT_GATEW  (N_TOK*DMODEL)
#define OUT_LOGITS (N_TOK*DMODEL + N_TOK*NE)

typedef short v8s __attribute__((ext_vector_type(8)));   // 8 bf16 (4 VGPR) MFMA A/B frag
typedef float v4f __attribute__((ext_vector_type(4)));   // 4 f32 MFMA C/D frag

__device__ __forceinline__ unsigned short f2bf(float f){   // RNE f32->bf16
  unsigned u = __float_as_uint(f);
  return (unsigned short)((u + 0x7FFFu + ((u>>16)&1u)) >> 16);
}
__device__ __forceinline__ float bf2f(unsigned short h){
  return __uint_as_float(((unsigned)h)<<16);
}
__device__ __forceinline__ float gelu_tanh(float v){
  float u = 0.7978845608028654f * (v + 0.044715f * v * v * v);
  float a = fabsf(u);
  float e = __expf(-2.0f * a);
  float t = (1.0f - e) / (1.0f + e);
  t = copysignf(t, u);
  return 0.5f * v * (1.0f + t);
}

// ---- prep: LDS-staged transpose to split-bf16 fragment planes ----
// frag layout: plane[((kstep*NT + nt))*64 + lane]*8+i
//   -> W[k=kstep*32+(lane>>4)*8+i][n=nt*16+(lane&15)]
__global__ __launch_bounds__(256) void k_prep(
    const float* __restrict__ We1, const float* __restrict__ We2,
    const float* __restrict__ Wr1,
    unsigned short* __restrict__ W1h, unsigned short* __restrict__ W1l,
    unsigned short* __restrict__ W2h, unsigned short* __restrict__ W2l,
    unsigned short* __restrict__ Wr1h, unsigned short* __restrict__ Wr1l,
    int* __restrict__ cnts, int* __restrict__ nfix)
{
  __shared__ float lds[16384];   // 64 KB: one 32-row K-slab
  const int b = blockIdx.x;
  const int tid = threadIdx.x;
  if (b < 80){                        // We1[e]: slab kstep (32 x 512)
    int e = b/10, kstep = b%10;
    const float* src = We1 + ((size_t)e*DIN + kstep*32)*DH;
    #pragma unroll
    for (int r=0;r<16;r++) ((float4*)lds)[r*256+tid] = ((const float4*)src)[r*256+tid];
    __syncthreads();
    #pragma unroll
    for (int r=0;r<8;r++){
      int ent = r*256+tid; int nt = ent>>6, l = ent&63;
      int n = nt*16 + (l&15); int k0 = (l>>4)*8;
      unsigned short hs[8], ls[8];
      #pragma unroll
      for (int i=0;i<8;i++){
        float v = lds[(k0+i)*DH + n];
        unsigned short h = f2bf(v);
        hs[i]=h; ls[i]=f2bf(v - bf2f(h));
      }
      size_t gid = ((size_t)(e*10+kstep)*32 + nt)*64 + l;
      *(v8s*)(W1h+gid*8) = *(v8s*)hs;
      *(v8s*)(W1l+gid*8) = *(v8s*)ls;
    }
  } else if (b < 208){                // We2[e]: slab kstep (32 x 256)
    int e = (b-80)/16, kstep = (b-80)%16;
    const float* src = We2 + ((size_t)e*DH + kstep*32)*DMODEL;
    #pragma unroll
    for (int r=0;r<8;r++) ((float4*)lds)[r*256+tid] = ((const float4*)src)[r*256+tid];
    __syncthreads();
    #pragma unroll
    for (int r=0;r<4;r++){
      int ent = r*256+tid; int nt = ent>>6, l = ent&63;
      int n = nt*16 + (l&15); int k0 = (l>>4)*8;
      unsigned short hs[8], ls[8];
      #pragma unroll
      for (int i=0;i<8;i++){
        float v = lds[(k0+i)*DMODEL + n];
        unsigned short h = f2bf(v);
        hs[i]=h; ls[i]=f2bf(v - bf2f(h));
      }
      size_t gid = ((size_t)(e*16+kstep)*16 + nt)*64 + l;
      *(v8s*)(W2h+gid*8) = *(v8s*)hs;
      *(v8s*)(W2l+gid*8) = *(v8s*)ls;
    }
  } else if (b < 218){                // Wr1: slab kstep (32 x 256)
    int kstep = b-208;
    const float* src = Wr1 + (size_t)kstep*32*DRTR;
    #pragma unroll
    for (int r=0;r<8;r++) ((float4*)lds)[r*256+tid] = ((const float4*)src)[r*256+tid];
    __syncthreads();
    #pragma unroll
    for (int r=0;r<4;r++){
      int ent = r*256+tid; int nt = ent>>6, l = ent&63;
      int n = nt*16 + (l&15); int k0 = (l>>4)*8;
      unsigned short hs[8], ls[8];
      #pragma unroll
      for (int i=0;i<8;i++){
        float v = lds[(k0+i)*DRTR + n];
        unsigned short h = f2bf(v);
        hs[i]=h; ls[i]=f2bf(v - bf2f(h));
      }
      size_t gid = ((size_t)kstep*16 + nt)*64 + l;
      *(v8s*)(Wr1h+gid*8) = *(v8s*)hs;
      *(v8s*)(Wr1l+gid*8) = *(v8s*)ls;
    }
  } else {                            // init
    if (tid < NE) cnts[tid] = 0;
    if (tid == NE) *nfix = 0;
  }
}

// mm6: split-bf16 triple product on two m-tiles (order fixed: bit-identical)
#define MM6(c0,c1,ah0,ah1,al0,al1,bh,bl) do{ \
  c0 = __builtin_amdgcn_mfma_f32_16x16x32_bf16(ah0, bh, c0, 0,0,0); \
  c1 = __builtin_amdgcn_mfma_f32_16x16x32_bf16(ah1, bh, c1, 0,0,0); \
  c0 = __builtin_amdgcn_mfma_f32_16x16x32_bf16(al0, bh, c0, 0,0,0); \
  c1 = __builtin_amdgcn_mfma_f32_16x16x32_bf16(al1, bh, c1, 0,0,0); \
  c0 = __builtin_amdgcn_mfma_f32_16x16x32_bf16(ah0, bl, c0, 0,0,0); \
  c1 = __builtin_amdgcn_mfma_f32_16x16x32_bf16(ah1, bl, c1, 0,0,0); }while(0)

#define XLOFF  10496   // router: ushort offset of xl plane ([32][328])

// ---- router: split-bf16 MFMA hr + fp32 logits; near-tie tokens deferred ----
__global__ __launch_bounds__(512) void k_rmfma(
    const float* __restrict__ hidden, const float* __restrict__ feat,
    const float* __restrict__ Wf, const float* __restrict__ bfe,
    const unsigned short* __restrict__ Wr1h, const unsigned short* __restrict__ Wr1l,
    const float* __restrict__ br1,
    const float* __restrict__ Wr2, const float* __restrict__ br2,
    float* __restrict__ out,
    int* __restrict__ cnts, unsigned* __restrict__ lists, float* __restrict__ topw,
    int* __restrict__ nfix, int* __restrict__ fixlist)
{
  __shared__ unsigned short sm[21248];   // xh@0 [32][328], xl@XLOFF; later hr f32 [32][264]
  __shared__ float part_lds[512];
  __shared__ float lg_lds[RTB*NE];
  float* hrf = (float*)sm;
  const int tid = threadIdx.x;
  const int t0 = blockIdx.x * RTB;

  {
    float4 z = make_float4(0.f,0.f,0.f,0.f);
    float4* dst = ((float4*)out) + (size_t)blockIdx.x*2048 + tid;
    #pragma unroll
    for (int r=0;r<4;r++) dst[r*512] = z;
  }
  #pragma unroll
  for (int r=0;r<4;r++){
    int idx = r*512 + tid; int t = idx >> 6, lane = idx & 63;
    float4 h4 = ((const float4*)(hidden + (size_t)(t0+t)*DMODEL))[lane];
    unsigned short h0=f2bf(h4.x),h1=f2bf(h4.y),h2=f2bf(h4.z),h3=f2bf(h4.w);
    unsigned short l0=f2bf(h4.x-bf2f(h0)),l1=f2bf(h4.y-bf2f(h1)),
                   l2=f2bf(h4.z-bf2f(h2)),l3=f2bf(h4.w-bf2f(h3));
    uint2 hp, lp;
    hp.x=(unsigned)h0|((unsigned)h1<<16); hp.y=(unsigned)h2|((unsigned)h3<<16);
    lp.x=(unsigned)l0|((unsigned)l1<<16); lp.y=(unsigned)l2|((unsigned)l3<<16);
    *(uint2*)&sm[t*328 + lane*4]         = hp;
    *(uint2*)&sm[XLOFF + t*328 + lane*4] = lp;
  }
  #pragma unroll
  for (int r=0;r<4;r++){
    int idx = r*512 + tid; int t = idx >> 6, j = idx & 63;
    float acc = bfe[j];
    #pragma unroll
    for (int f=0; f<NFEAT; f++) acc += feat[(size_t)(t0+t)*NFEAT + f] * Wf[f*DFEAT + j];
    unsigned short h = f2bf(acc);
    sm[t*328 + DMODEL + j]         = h;
    sm[XLOFF + t*328 + DMODEL + j] = f2bf(acc - bf2f(h));
  }
  __syncthreads();

  const int wv = tid >> 6;
  const int l  = tid & 63;
  const int lg = l >> 4;
  const int lr = l & 15;

  v4f acc[2][2];
  {
    v4f z = {0.f,0.f,0.f,0.f};
    acc[0][0]=z; acc[0][1]=z; acc[1][0]=z; acc[1][1]=z;
    v8s bh_a[2], bl_a[2], bh_b[2], bl_b[2];
    auto ldBr = [&](int ks, v8s (&bh)[2], v8s (&bl)[2]){
      #pragma unroll
      for (int j=0;j<2;++j){
        size_t boff = ((size_t)(ks*16 + wv*2 + j)*64 + l)*8;
        bh[j] = *(const v8s*)(Wr1h + boff);
        bl[j] = *(const v8s*)(Wr1l + boff);
      }
    };
    ldBr(0, bh_a, bl_a);
    for (int ks=0; ks<10; ks+=2){
      v8s ah0 = *(const v8s*)&sm[( 0+lr)*328 + ks*32 + lg*8];
      v8s ah1 = *(const v8s*)&sm[(16+lr)*328 + ks*32 + lg*8];
      v8s al0 = *(const v8s*)&sm[XLOFF + ( 0+lr)*328 + ks*32 + lg*8];
      v8s al1 = *(const v8s*)&sm[XLOFF + (16+lr)*328 + ks*32 + lg*8];
      ldBr(ks+1, bh_b, bl_b);
      __builtin_amdgcn_sched_barrier(0);   // pin prefetch above MFMAs
      #pragma unroll
      for (int j=0;j<2;++j) MM6(acc[0][j],acc[1][j], ah0,ah1,al0,al1, bh_a[j],bl_a[j]);
      v8s ch0 = *(const v8s*)&sm[( 0+lr)*328 + (ks+1)*32 + lg*8];
      v8s ch1 = *(const v8s*)&sm[(16+lr)*328 + (ks+1)*32 + lg*8];
      v8s cl0 = *(const v8s*)&sm[XLOFF + ( 0+lr)*328 + (ks+1)*32 + lg*8];
      v8s cl1 = *(const v8s*)&sm[XLOFF + (16+lr)*328 + (ks+1)*32 + lg*8];
      if (ks+2<10) ldBr(ks+2, bh_a, bl_a);
      __builtin_amdgcn_sched_barrier(0);
      #pragma unroll
      for (int j=0;j<2;++j) MM6(acc[0][j],acc[1][j], ch0,ch1,cl0,cl1, bh_b[j],bl_b[j]);
    }
  }
  __syncthreads();
  #pragma unroll
  for (int j=0;j<2;++j){
    int col = (wv*2+j)*16 + lr;
    float b1 = br1[col];
    #pragma unroll
    for (int m=0;m<2;m++)
      #pragma unroll
      for (int r=0;r<4;r++){
        int row = m*16 + lg*4 + r;
        hrf[row*264 + col] = gelu_tanh(acc[m][j][r] + b1);
      }
  }
  __syncthreads();
  {
    int q = tid >> 8, rr = tid & 255, t = rr >> 3, e = rr & 7;
    float a0=0.f,a1=0.f,a2=0.f,a3=0.f;
    #pragma unroll 4
    for (int k4=0;k4<32;k4++){
      float4 h4 = ((const float4*)hrf)[t*66 + q*32 + k4];
      int row = q*128 + k4*4;
      a0 += h4.x * Wr2[(row+0)*NE + e];
      a1 += h4.y * Wr2[(row+1)*NE + e];
      a2 += h4.z * Wr2[(row+2)*NE + e];
      a3 += h4.w * Wr2[(row+3)*NE + e];
    }
    part_lds[tid] = (a0+a1)+(a2+a3);
  }
  __syncthreads();
  if (tid < RTB*NE){
    int t = tid >> 3, e = tid & 7;
    float lgv = br2[e] + part_lds[tid] + part_lds[tid+256];
    out[OUT_LOGITS + (size_t)(t0+t)*NE + e] = lgv;   // TEMP == 1.0
    lg_lds[t*NE + e] = lgv;
  }
  __syncthreads();
  if (tid < RTB){
    int t = tid, tok = t0 + t;
    float v1=-3.4e38f, v2=-3.4e38f, v3=-3.4e38f; int i1=-1, i2=-1;
    #pragma unroll
    for (int e=0;e<NE;e++){
      float v = lg_lds[t*NE+e];
      if (v > v1){ v3=v2; v2=v1; i2=i1; v1=v; i1=e; }
      else if (v > v2){ v3=v2; v2=v; i2=e; }
      else if (v > v3){ v3=v; }
    }
    bool defer = false;
    if (v2 - v3 < FIXTHR){
      int fi = atomicAdd(nfix, 1);
      if (fi < FIXCAP){ fixlist[fi] = tok; defer = true; }
    }
    if (!defer){
      float d   = expf(v2 - v1);
      float inv = 1.0f/(1.0f + d);
      float w1 = inv, w2 = d*inv;
      #pragma unroll
      for (int e=0;e<NE;e++){
        float gv = (e==i1) ? w1 : ((e==i2) ? w2 : 0.f);
        out[OUT_GATEW + (size_t)tok*NE + e] = gv;
      }
      int p1 = atomicAdd(&cnts[i1], 1);
      lists[i1*N_TOK + p1] = (unsigned)(tok<<1);
      int p2 = atomicAdd(&cnts[i2], 1);
      lists[i2*N_TOK + p2] = (unsigned)((tok<<1) | 1);
      topw[tok*2]   = w1;
      topw[tok*2+1] = w2;
    }
  }
}

// ---- exact fp32 recompute of logits for flagged tokens (rare) ----
__global__ __launch_bounds__(256) void k_fix(
    const float* __restrict__ hidden, const float* __restrict__ feat,
    const float* __restrict__ Wf, const float* __restrict__ bfe,
    const float* __restrict__ Wr1, const float* __restrict__ br1,
    const float* __restrict__ Wr2, const float* __restrict__ br2,
    float* __restrict__ out, const int* __restrict__ nfix, const int* __restrict__ fixlist)
{
  int nf = *nfix; if (nf > FIXCAP) nf = FIXCAP;
  if ((int)blockIdx.x >= nf) return;
  const int tok = fixlist[blockIdx.x];
  const int tid = threadIdx.x;
  __shared__ float xf[DIN];
  __shared__ float hr[DRTR];
  if (tid < DMODEL) xf[tid] = hidden[(size_t)tok*DMODEL + tid];
  if (tid < DFEAT){
    float acc = bfe[tid];
    #pragma unroll
    for (int f=0; f<NFEAT; f++) acc += feat[(size_t)tok*NFEAT + f] * Wf[f*DFEAT + tid];
    xf[DMODEL + tid] = acc;
  }
  __syncthreads();
  {
    float acc = br1[tid];
    for (int i=0;i<DIN;i++) acc += xf[i] * Wr1[(size_t)i*DRTR + tid];
    hr[tid] = gelu_tanh(acc);
  }
  __syncthreads();
  if (tid < NE){
    float acc = br2[tid];
    for (int i=0;i<DRTR;i++) acc += hr[i] * Wr2[i*NE + tid];
    out[OUT_LOGITS + (size_t)tok*NE + tid] = acc;
  }
}

// ---- gate the flagged tokens from final (exact) logits ----
__global__ void k_gatefix(float* __restrict__ out,
                          int* __restrict__ cnts, unsigned* __restrict__ lists,
                          float* __restrict__ topw,
                          const int* __restrict__ nfix, const int* __restrict__ fixlist)
{
  int nf = *nfix; if (nf > FIXCAP) nf = FIXCAP;
  int i = threadIdx.x;
  if (i >= nf) return;
  int tok = fixlist[i];
  float v1=-3.4e38f, v2=-3.4e38f; int i1=-1, i2=-1;
  #pragma unroll
  for (int e=0;e<NE;e++){
    float v = out[OUT_LOGITS + (size_t)tok*NE + e];
    if (v > v1){ v2=v1; i2=i1; v1=v; i1=e; }
    else if (v > v2){ v2=v; i2=e; }
  }
  float d   = expf(v2 - v1);
  float inv = 1.0f/(1.0f + d);
  float w1 = inv, w2 = d*inv;
  #pragma unroll
  for (int e=0;e<NE;e++){
    float gv = (e==i1) ? w1 : ((e==i2) ? w2 : 0.f);
    out[OUT_GATEW + (size_t)tok*NE + e] = gv;
  }
  int p1 = atomicAdd(&cnts[i1], 1);
  lists[i1*N_TOK + p1] = (unsigned)(tok<<1);
  int p2 = atomicAdd(&cnts[i2], 1);
  lists[i2*N_TOK + p2] = (unsigned)((tok<<1) | 1);
  topw[tok*2]   = w1;
  topw[tok*2+1] = w2;
}

// ---- expert: TE=32, 8 waves; fragment-linear LDS (zero-conflict ds_read_b128);
//      sched_barrier-pinned double-buffered B prefetch ----
// A planes (x):  xfh[(ks*2+m)*64+l][8] @0 (10240 us), xfl @10240
// he planes:     hfh[(ks2*2+m)*64+l][8] @0 (16384 us), hfl @16384  (union)
#define XFL  10240
#define HFL  16384
__global__ __launch_bounds__(512) void k_expert(
    const float* __restrict__ hidden, const float* __restrict__ feat,
    const float* __restrict__ Wf, const float* __restrict__ bfe,
    const int* __restrict__ cnts, const unsigned* __restrict__ lists,
    const float* __restrict__ topw,
    const unsigned short* __restrict__ W1h, const unsigned short* __restrict__ W1l,
    const unsigned short* __restrict__ W2h, const unsigned short* __restrict__ W2l,
    const float* __restrict__ be1, const float* __restrict__ be2,
    float* __restrict__ out)
{
  __shared__ unsigned short sm[32768];   // 65536 B union: x frags -> he frags
  __shared__ int   tok_lds[TE];
  __shared__ float w_lds[TE];

  const int e    = blockIdx.x & 7;      // expert pins to XCD e (weights L2-hot)
  const int tile = blockIdx.x >> 3;
  const int cnt  = cnts[e];
  const int start = tile * TE;
  if (start >= cnt) return;
  const int ntk = min(TE, cnt - start);
  const int tid = threadIdx.x;
  const int wv = tid >> 6;      // wave 0..7
  const int l  = tid & 63;
  const int lg = l >> 4;
  const int lr = l & 15;

  const unsigned short* p1h = W1h + (size_t)e*163840;
  const unsigned short* p1l = W1l + (size_t)e*163840;

  // early B prefetch for phase-1 ks=0 half 0 (independent of staging)
  v8s bh_a[2], bl_a[2], bh_b[2], bl_b[2];
  auto ldB1 = [&](int ks, int jh, v8s (&bh)[2], v8s (&bl)[2]){
    #pragma unroll
    for (int j=0;j<2;++j){
      size_t boff = ((size_t)(ks*32 + wv*4 + jh*2 + j)*64 + l)*8;
      bh[j] = *(const v8s*)(p1h + boff);
      bl[j] = *(const v8s*)(p1l + boff);
    }
  };
  ldB1(0,0,bh_a,bl_a);

  if (tid < TE){
    if (tid < ntk){
      unsigned ent = lists[e*N_TOK + start + tid];
      int tok = (int)(ent >> 1);
      tok_lds[tid] = tok;
      w_lds[tid]   = topw[tok*2 + (ent & 1)];
    } else { tok_lds[tid] = -1; w_lds[tid] = 0.f; }
  }
  __syncthreads();
  // stage x split-bf16 DIRECTLY in fragment order: entry idx=(ks*2+m)*64+l
  //   token t = m*16 + (l&15), k-range kb = ks*32 + (l>>4)*8
  #pragma unroll
  for (int r=0;r<3;r++){
    int idx = r*512 + tid;
    if (idx < 1280){
      int le = idx & 63; int rest = idx >> 6;
      int m = rest & 1, ks = rest >> 1;
      int t = m*16 + (le & 15);
      int kb = ks*32 + (le >> 4)*8;
      int tok = tok_lds[t];
      float v[8];
      if (tok < 0){
        #pragma unroll
        for (int i=0;i<8;i++) v[i] = 0.f;
      } else if (kb < DMODEL){
        float4 a = *(const float4*)(hidden + (size_t)tok*DMODEL + kb);
        float4 b = *(const float4*)(hidden + (size_t)tok*DMODEL + kb + 4);
        v[0]=a.x; v[1]=a.y; v[2]=a.z; v[3]=a.w;
        v[4]=b.x; v[5]=b.y; v[6]=b.z; v[7]=b.w;
      } else {
        int j0 = kb - DMODEL;
        #pragma unroll
        for (int i=0;i<8;i++){
          float acc = bfe[j0+i];
          #pragma unroll
          for (int f=0; f<NFEAT; f++) acc += feat[(size_t)tok*NFEAT + f] * Wf[f*DFEAT + j0+i];
          v[i] = acc;
        }
      }
      unsigned short hs[8], ls[8];
      #pragma unroll
      for (int i=0;i<8;i++){
        unsigned short h = f2bf(v[i]);
        hs[i]=h; ls[i]=f2bf(v[i]-bf2f(h));
      }
      *(v8s*)&sm[idx*8]       = *(v8s*)hs;
      *(v8s*)&sm[XFL + idx*8] = *(v8s*)ls;
    }
  }
  __syncthreads();

  // phase 1: he = gelu(x @ We1[e] + be1); wave owns 4 n-tiles (2+2 halves)
  v4f acc1[2][4];
  {
    v4f z = {0.f,0.f,0.f,0.f};
    #pragma unroll
    for (int m=0;m<2;m++)
      #pragma unroll
      for (int j=0;j<4;j++) acc1[m][j] = z;
    for (int ks=0; ks<10; ++ks){
      v8s ah0 = *(const v8s*)&sm[((ks*2+0)*64 + l)*8];        // lane-linear: 0 conflicts
      v8s ah1 = *(const v8s*)&sm[((ks*2+1)*64 + l)*8];
      v8s al0 = *(const v8s*)&sm[XFL + ((ks*2+0)*64 + l)*8];
      v8s al1 = *(const v8s*)&sm[XFL + ((ks*2+1)*64 + l)*8];
      ldB1(ks,1,bh_b,bl_b);                                   // issue half-1 B
      __builtin_amdgcn_sched_barrier(0);                      // pin loads above MFMAs
      #pragma unroll
      for (int j=0;j<2;++j) MM6(acc1[0][j],acc1[1][j], ah0,ah1,al0,al1, bh_a[j],bl_a[j]);
      if (ks<9) ldB1(ks+1,0,bh_a,bl_a);                       // issue next-ks half-0 B
      __builtin_amdgcn_sched_barrier(0);
      #pragma unroll
      for (int j=0;j<2;++j) MM6(acc1[0][2+j],acc1[1][2+j], ah0,ah1,al0,al1, bh_b[j],bl_b[j]);
    }
  }
  // early B prefetch for phase-2 ks=0 (independent of he LDS)
  const unsigned short* p2h = W2h + (size_t)e*131072;
  const unsigned short* p2l = W2l + (size_t)e*131072;
  v8s ch_a[2], cl_a[2], ch_b[2], cl_b[2];
  auto ldB2 = [&](int ks, v8s (&bh)[2], v8s (&bl)[2]){
    #pragma unroll
    for (int j=0;j<2;++j){
      size_t boff = ((size_t)(ks*16 + wv*2 + j)*64 + l)*8;
      bh[j] = *(const v8s*)(p2h + boff);
      bl[j] = *(const v8s*)(p2l + boff);
    }
  };
  ldB2(0, ch_a, cl_a);
  __syncthreads();   // x frags dead -> he frags
  // epilogue 1: bias+gelu+split, write he in PHASE-2 FRAGMENT ORDER
  #pragma unroll
  for (int j=0;j<4;++j){
    int W = wv*4 + j;                 // n-tile 0..31
    int col = W*16 + lr;
    float b1 = be1[e*DH + col];
    int ks2 = W >> 1;
    int lg2 = (W*2 + (lr>>3)) & 3;
    int i   = lr & 7;
    #pragma unroll
    for (int m=0;m<2;m++)
      #pragma unroll
      for (int r=0;r<4;r++){
        float v = gelu_tanh(acc1[m][j][r] + b1);
        unsigned short h = f2bf(v);
        int dst = ((ks2*2 + m)*64 + lg2*16 + lg*4 + r)*8 + i;
        sm[dst]       = h;
        sm[HFL + dst] = f2bf(v - bf2f(h));
      }
  }
  __syncthreads();
  // phase 2: eo = he @ We2[e] + be2; wave owns 2 n-tiles
  v4f acc2[2][2];
  {
    v4f z = {0.f,0.f,0.f,0.f};
    acc2[0][0]=z; acc2[0][1]=z; acc2[1][0]=z; acc2[1][1]=z;
    for (int ks=0; ks<16; ks+=2){
      v8s ah0 = *(const v8s*)&sm[((ks*2+0)*64 + l)*8];
      v8s ah1 = *(const v8s*)&sm[((ks*2+1)*64 + l)*8];
      v8s al0 = *(const v8s*)&sm[HFL + ((ks*2+0)*64 + l)*8];
      v8s al1 = *(const v8s*)&sm[HFL + ((ks*2+1)*64 + l)*8];
      ldB2(ks+1, ch_b, cl_b);
      __builtin_amdgcn_sched_barrier(0);
      #pragma unroll
      for (int j=0;j<2;++j) MM6(acc2[0][j],acc2[1][j], ah0,ah1,al0,al1, ch_a[j],cl_a[j]);
      v8s dh0 = *(const v8s*)&sm[(((ks+1)*2+0)*64 + l)*8];
      v8s dh1 = *(const v8s*)&sm[(((ks+1)*2+1)*64 + l)*8];
      v8s dl0 = *(const v8s*)&sm[HFL + (((ks+1)*2+0)*64 + l)*8];
      v8s dl1 = *(const v8s*)&sm[HFL + (((ks+1)*2+1)*64 + l)*8];
      if (ks+2<16) ldB2(ks+2, ch_a, cl_a);
      __builtin_amdgcn_sched_barrier(0);
      #pragma unroll
      for (int j=0;j<2;++j) MM6(acc2[0][j],acc2[1][j], dh0,dh1,dl0,dl1, ch_b[j],cl_b[j]);
    }
  }
  // epilogue 2: + be2, * gate, atomicAdd into stage_delta
  #pragma unroll
  for (int j=0;j<2;++j){
    int col = (wv*2+j)*16 + lr;
    float b2 = be2[e*DMODEL + col];
    #pragma unroll
    for (int m=0;m<2;m++)
      #pragma unroll
      for (int r=0;r<4;r++){
        int row = m*16 + lg*4 + r;
        if (row < ntk){
          float w = w_lds[row];
          atomicAdd(out + (size_t)tok_lds[row]*DMODEL + col,
                    w*(acc2[m][j][r] + b2));
        }
      }
  }
}

extern "C" void kernel_launch(void* const* d_in, const int* in_sizes, int n_in,
                              void* d_out, int out_size, void* d_ws, size_t ws_size,
                              hipStream_t stream)
{
  (void)in_sizes; (void)n_in; (void)out_size; (void)ws_size;
  const float* hidden = (const float*)d_in[0];
  const float* feat   = (const float*)d_in[1];
  const float* Wf     = (const float*)d_in[2];
  const float* bfe    = (const float*)d_in[3];
  const float* Wr1    = (const float*)d_in[4];
  const float* br1    = (const float*)d_in[5];
  const float* Wr2    = (const float*)d_in[6];
  const float* br2    = (const float*)d_in[7];
  const float* We1    = (const float*)d_in[8];
  const float* be1    = (const float*)d_in[9];
  const float* We2    = (const float*)d_in[10];
  const float* be2    = (const float*)d_in[11];
  float* out = (float*)d_out;

  // ws layout (bytes): cnts@0(8i) nfix@64 fixlist@128(128i) lists@1024 topw@263168
  //   W1h@328704 W1l@2950144 W2h@5571584 W2l@7668736 Wr1h@9765888 Wr1l@9929728 (~10.1MB)
  char* ws = (char*)d_ws;
  int*      cnts    = (int*)ws;
  int*      nfix    = (int*)(ws + 64);
  int*      fixlist = (int*)(ws + 128);
  unsigned* lists   = (unsigned*)(ws + 1024);
  float*    topw    = (float*)(ws + 263168);
  unsigned short* W1h  = (unsigned short*)(ws + 328704);
  unsigned short* W1l  = (unsigned short*)(ws + 2950144);
  unsigned short* W2h  = (unsigned short*)(ws + 5571584);
  unsigned short* W2l  = (unsigned short*)(ws + 7668736);
  unsigned short* Wr1h = (unsigned short*)(ws + 9765888);
  unsigned short* Wr1l = (unsigned short*)(ws + 9929728);

  hipLaunchKernelGGL(k_prep, dim3(219), dim3(256), 0, stream,
                     We1, We2, Wr1, W1h, W1l, W2h, W2l, Wr1h, Wr1l, cnts, nfix);
  hipLaunchKernelGGL(k_rmfma, dim3(N_TOK/RTB), dim3(512), 0, stream,
                     hidden, feat, Wf, bfe, Wr1h, Wr1l, br1, Wr2, br2,
                     out, cnts, lists, topw, nfix, fixlist);
  hipLaunchKernelGGL(k_fix, dim3(FIXCAP), dim3(256), 0, stream,
                     hidden, feat, Wf, bfe, Wr1, br1, Wr2, br2, out, nfix, fixlist);
  hipLaunchKernelGGL(k_gatefix, dim3(1), dim3(FIXCAP), 0, stream,
                     out, cnts, lists, topw, nfix, fixlist);
  hipLaunchKernelGGL(k_expert, dim3((N_TOK/TE)*NE), dim3(512), 0, stream,
                     hidden, feat, Wf, bfe, cnts, lists, topw,
                     W1h, W1l, W2h, W2l, be1, be2, out);
}

// Round 12
// 270.108 us; speedup vs baseline: 1.1488x; 1.1488x over previous
//
#include <hip/hip_runtime.h>
#include <hip/hip_bf16.h>

// Problem: B=32, L=256 -> 8192 tokens; DIN=320, DR=256, DH=512, E=8, top-2.
#define N_TOK   8192
#define DMODEL  256
#define NFEAT   8
#define DFEAT   64
#define DIN     320
#define DRTR    256
#define NE      8
#define DH      512
#define TE      32      // tokens per expert tile (2 m-tiles)
#define RTB     16      // tokens per router block (512 blocks -> 2/CU)
#define FIXCAP  128
#define FIXTHR  2e-3f

// d_out layout (floats): [stage_delta 8192*256][gate_weights 8192*8][gate_logits 8192*8]
#define OUT_GATEW  (N_TOK*DMODEL)
#define OUT_LOGITS (N_TOK*DMODEL + N_TOK*NE)

typedef short v8s __attribute__((ext_vector_type(8)));   // 8 bf16 (4 VGPR) MFMA A/B frag
typedef float v4f __attribute__((ext_vector_type(4)));   // 4 f32 MFMA C/D frag

__device__ __forceinline__ unsigned short f2bf(float f){   // RNE f32->bf16
  unsigned u = __float_as_uint(f);
  return (unsigned short)((u + 0x7FFFu + ((u>>16)&1u)) >> 16);
}
__device__ __forceinline__ float bf2f(unsigned short h){
  return __uint_as_float(((unsigned)h)<<16);
}
__device__ __forceinline__ float gelu_tanh(float v){
  float u = 0.7978845608028654f * (v + 0.044715f * v * v * v);
  float a = fabsf(u);
  float e = __expf(-2.0f * a);
  float t = (1.0f - e) / (1.0f + e);
  t = copysignf(t, u);
  return 0.5f * v * (1.0f + t);
}

// ---- prep: LDS-staged transpose to split-bf16 fragment planes ----
__global__ __launch_bounds__(256) void k_prep(
    const float* __restrict__ We1, const float* __restrict__ We2,
    const float* __restrict__ Wr1,
    unsigned short* __restrict__ W1h, unsigned short* __restrict__ W1l,
    unsigned short* __restrict__ W2h, unsigned short* __restrict__ W2l,
    unsigned short* __restrict__ Wr1h, unsigned short* __restrict__ Wr1l,
    int* __restrict__ cnts, int* __restrict__ nfix)
{
  __shared__ float lds[16384];   // 64 KB: one 32-row K-slab
  const int b = blockIdx.x;
  const int tid = threadIdx.x;
  if (b < 80){                        // We1[e]: slab kstep (32 x 512)
    int e = b/10, kstep = b%10;
    const float* src = We1 + ((size_t)e*DIN + kstep*32)*DH;
    #pragma unroll
    for (int r=0;r<16;r++) ((float4*)lds)[r*256+tid] = ((const float4*)src)[r*256+tid];
    __syncthreads();
    #pragma unroll
    for (int r=0;r<8;r++){
      int ent = r*256+tid; int nt = ent>>6, l = ent&63;
      int n = nt*16 + (l&15); int k0 = (l>>4)*8;
      unsigned short hs[8], ls[8];
      #pragma unroll
      for (int i=0;i<8;i++){
        float v = lds[(k0+i)*DH + n];
        unsigned short h = f2bf(v);
        hs[i]=h; ls[i]=f2bf(v - bf2f(h));
      }
      size_t gid = ((size_t)(e*10+kstep)*32 + nt)*64 + l;
      *(v8s*)(W1h+gid*8) = *(v8s*)hs;
      *(v8s*)(W1l+gid*8) = *(v8s*)ls;
    }
  } else if (b < 208){                // We2[e]: slab kstep (32 x 256)
    int e = (b-80)/16, kstep = (b-80)%16;
    const float* src = We2 + ((size_t)e*DH + kstep*32)*DMODEL;
    #pragma unroll
    for (int r=0;r<8;r++) ((float4*)lds)[r*256+tid] = ((const float4*)src)[r*256+tid];
    __syncthreads();
    #pragma unroll
    for (int r=0;r<4;r++){
      int ent = r*256+tid; int nt = ent>>6, l = ent&63;
      int n = nt*16 + (l&15); int k0 = (l>>4)*8;
      unsigned short hs[8], ls[8];
      #pragma unroll
      for (int i=0;i<8;i++){
        float v = lds[(k0+i)*DMODEL + n];
        unsigned short h = f2bf(v);
        hs[i]=h; ls[i]=f2bf(v - bf2f(h));
      }
      size_t gid = ((size_t)(e*16+kstep)*16 + nt)*64 + l;
      *(v8s*)(W2h+gid*8) = *(v8s*)hs;
      *(v8s*)(W2l+gid*8) = *(v8s*)ls;
    }
  } else if (b < 218){                // Wr1: slab kstep (32 x 256)
    int kstep = b-208;
    const float* src = Wr1 + (size_t)kstep*32*DRTR;
    #pragma unroll
    for (int r=0;r<8;r++) ((float4*)lds)[r*256+tid] = ((const float4*)src)[r*256+tid];
    __syncthreads();
    #pragma unroll
    for (int r=0;r<4;r++){
      int ent = r*256+tid; int nt = ent>>6, l = ent&63;
      int n = nt*16 + (l&15); int k0 = (l>>4)*8;
      unsigned short hs[8], ls[8];
      #pragma unroll
      for (int i=0;i<8;i++){
        float v = lds[(k0+i)*DRTR + n];
        unsigned short h = f2bf(v);
        hs[i]=h; ls[i]=f2bf(v - bf2f(h));
      }
      size_t gid = ((size_t)kstep*16 + nt)*64 + l;
      *(v8s*)(Wr1h+gid*8) = *(v8s*)hs;
      *(v8s*)(Wr1l+gid*8) = *(v8s*)ls;
    }
  } else {                            // init
    if (tid < NE) cnts[tid] = 0;
    if (tid == NE) *nfix = 0;
  }
}

// MM6: split-bf16 triple product on two m-tiles (per-acc order bit-identical)
#define MM6(c0,c1,ah0,ah1,al0,al1,bh,bl) do{ \
  c0 = __builtin_amdgcn_mfma_f32_16x16x32_bf16(ah0, bh, c0, 0,0,0); \
  c1 = __builtin_amdgcn_mfma_f32_16x16x32_bf16(ah1, bh, c1, 0,0,0); \
  c0 = __builtin_amdgcn_mfma_f32_16x16x32_bf16(al0, bh, c0, 0,0,0); \
  c1 = __builtin_amdgcn_mfma_f32_16x16x32_bf16(al1, bh, c1, 0,0,0); \
  c0 = __builtin_amdgcn_mfma_f32_16x16x32_bf16(ah0, bl, c0, 0,0,0); \
  c1 = __builtin_amdgcn_mfma_f32_16x16x32_bf16(ah1, bl, c1, 0,0,0); }while(0)
// MM3: single m-tile variant (router, 16 tokens)
#define MM3(c0,ah0,al0,bh,bl) do{ \
  c0 = __builtin_amdgcn_mfma_f32_16x16x32_bf16(ah0, bh, c0, 0,0,0); \
  c0 = __builtin_amdgcn_mfma_f32_16x16x32_bf16(al0, bh, c0, 0,0,0); \
  c0 = __builtin_amdgcn_mfma_f32_16x16x32_bf16(ah0, bl, c0, 0,0,0); }while(0)

#define XLOFF  5248    // router: ushort offset of xl plane ([16][328])

// ---- router: split-bf16 MFMA hr + fp32 logits; near-tie tokens deferred ----
// 512 blocks x 512 thr (2 blocks/CU).
__global__ __launch_bounds__(512) void k_rmfma(
    const float* __restrict__ hidden, const float* __restrict__ feat,
    const float* __restrict__ Wf, const float* __restrict__ bfe,
    const unsigned short* __restrict__ Wr1h, const unsigned short* __restrict__ Wr1l,
    const float* __restrict__ br1,
    const float* __restrict__ Wr2, const float* __restrict__ br2,
    float* __restrict__ out,
    int* __restrict__ cnts, unsigned* __restrict__ lists, float* __restrict__ topw,
    int* __restrict__ nfix, int* __restrict__ fixlist)
{
  __shared__ unsigned short sm[10496];   // xh@0 [16][328], xl@XLOFF; later hr f32 [16][264]
  __shared__ float part_lds[512];
  __shared__ float lg_lds[RTB*NE];
  float* hrf = (float*)sm;
  const int tid = threadIdx.x;
  const int t0 = blockIdx.x * RTB;

  // zero this block's stage_delta slab (16*256 floats = 1024 f4)
  {
    float4 z = make_float4(0.f,0.f,0.f,0.f);
    float4* dst = ((float4*)out) + (size_t)blockIdx.x*1024 + tid;
    dst[0] = z; dst[512] = z;
  }
  #pragma unroll
  for (int r=0;r<2;r++){
    int idx = r*512 + tid; int t = idx >> 6, lane = idx & 63;
    float4 h4 = ((const float4*)(hidden + (size_t)(t0+t)*DMODEL))[lane];
    unsigned short h0=f2bf(h4.x),h1=f2bf(h4.y),h2=f2bf(h4.z),h3=f2bf(h4.w);
    unsigned short l0=f2bf(h4.x-bf2f(h0)),l1=f2bf(h4.y-bf2f(h1)),
                   l2=f2bf(h4.z-bf2f(h2)),l3=f2bf(h4.w-bf2f(h3));
    uint2 hp, lp;
    hp.x=(unsigned)h0|((unsigned)h1<<16); hp.y=(unsigned)h2|((unsigned)h3<<16);
    lp.x=(unsigned)l0|((unsigned)l1<<16); lp.y=(unsigned)l2|((unsigned)l3<<16);
    *(uint2*)&sm[t*328 + lane*4]         = hp;
    *(uint2*)&sm[XLOFF + t*328 + lane*4] = lp;
  }
  #pragma unroll
  for (int r=0;r<2;r++){
    int idx = r*512 + tid; int t = idx >> 6, j = idx & 63;
    float acc = bfe[j];
    #pragma unroll
    for (int f=0; f<NFEAT; f++) acc += feat[(size_t)(t0+t)*NFEAT + f] * Wf[f*DFEAT + j];
    unsigned short h = f2bf(acc);
    sm[t*328 + DMODEL + j]         = h;
    sm[XLOFF + t*328 + DMODEL + j] = f2bf(acc - bf2f(h));
  }
  __syncthreads();

  const int wv = tid >> 6;
  const int l  = tid & 63;
  const int lg = l >> 4;
  const int lr = l & 15;

  v4f acc[2];
  {
    v4f z = {0.f,0.f,0.f,0.f};
    acc[0]=z; acc[1]=z;
    v8s bh_a[2], bl_a[2], bh_b[2], bl_b[2];
    auto ldBr = [&](int ks, v8s (&bh)[2], v8s (&bl)[2]){
      #pragma unroll
      for (int j=0;j<2;++j){
        size_t boff = ((size_t)(ks*16 + wv*2 + j)*64 + l)*8;
        bh[j] = *(const v8s*)(Wr1h + boff);
        bl[j] = *(const v8s*)(Wr1l + boff);
      }
    };
    ldBr(0, bh_a, bl_a);
    for (int ks=0; ks<10; ks+=2){
      v8s ah0 = *(const v8s*)&sm[lr*328 + ks*32 + lg*8];
      v8s al0 = *(const v8s*)&sm[XLOFF + lr*328 + ks*32 + lg*8];
      ldBr(ks+1, bh_b, bl_b);
      #pragma unroll
      for (int j=0;j<2;++j) MM3(acc[j], ah0,al0, bh_a[j],bl_a[j]);
      v8s ch0 = *(const v8s*)&sm[lr*328 + (ks+1)*32 + lg*8];
      v8s cl0 = *(const v8s*)&sm[XLOFF + lr*328 + (ks+1)*32 + lg*8];
      if (ks+2<10) ldBr(ks+2, bh_a, bl_a);
      #pragma unroll
      for (int j=0;j<2;++j) MM3(acc[j], ch0,cl0, bh_b[j],bl_b[j]);
    }
  }
  __syncthreads();
  #pragma unroll
  for (int j=0;j<2;++j){
    int col = (wv*2+j)*16 + lr;
    float b1 = br1[col];
    #pragma unroll
    for (int r=0;r<4;r++){
      int row = lg*4 + r;
      hrf[row*264 + col] = gelu_tanh(acc[j][r] + b1);
    }
  }
  __syncthreads();
  // logits: 4-way k-split; tid = q*128 + t*8 + e
  {
    int q = tid >> 7, rr = tid & 127, t = rr >> 3, e = rr & 7;
    float a0=0.f,a1=0.f,a2=0.f,a3=0.f;
    #pragma unroll 4
    for (int k4=0;k4<16;k4++){
      float4 h4 = ((const float4*)hrf)[t*66 + q*16 + k4];
      int row = q*64 + k4*4;
      a0 += h4.x * Wr2[(row+0)*NE + e];
      a1 += h4.y * Wr2[(row+1)*NE + e];
      a2 += h4.z * Wr2[(row+2)*NE + e];
      a3 += h4.w * Wr2[(row+3)*NE + e];
    }
    part_lds[tid] = (a0+a1)+(a2+a3);
  }
  __syncthreads();
  if (tid < RTB*NE){
    int t = tid >> 3, e = tid & 7;
    float lgv = br2[e] + part_lds[tid] + part_lds[tid+128] + part_lds[tid+256] + part_lds[tid+384];
    out[OUT_LOGITS + (size_t)(t0+t)*NE + e] = lgv;   // TEMP == 1.0
    lg_lds[t*NE + e] = lgv;
  }
  __syncthreads();
  if (tid < RTB){
    int t = tid, tok = t0 + t;
    float v1=-3.4e38f, v2=-3.4e38f, v3=-3.4e38f; int i1=-1, i2=-1;
    #pragma unroll
    for (int e=0;e<NE;e++){
      float v = lg_lds[t*NE+e];
      if (v > v1){ v3=v2; v2=v1; i2=i1; v1=v; i1=e; }
      else if (v > v2){ v3=v2; v2=v; i2=e; }
      else if (v > v3){ v3=v; }
    }
    bool defer = false;
    if (v2 - v3 < FIXTHR){
      int fi = atomicAdd(nfix, 1);
      if (fi < FIXCAP){ fixlist[fi] = tok; defer = true; }
    }
    if (!defer){
      float d   = expf(v2 - v1);
      float inv = 1.0f/(1.0f + d);
      float w1 = inv, w2 = d*inv;
      #pragma unroll
      for (int e=0;e<NE;e++){
        float gv = (e==i1) ? w1 : ((e==i2) ? w2 : 0.f);
        out[OUT_GATEW + (size_t)tok*NE + e] = gv;
      }
      int p1 = atomicAdd(&cnts[i1], 1);
      lists[i1*N_TOK + p1] = (unsigned)(tok<<1);
      int p2 = atomicAdd(&cnts[i2], 1);
      lists[i2*N_TOK + p2] = (unsigned)((tok<<1) | 1);
      topw[tok*2]   = w1;
      topw[tok*2+1] = w2;
    }
  }
}

// ---- exact fp32 recompute of logits for flagged tokens (rare) ----
__global__ __launch_bounds__(256) void k_fix(
    const float* __restrict__ hidden, const float* __restrict__ feat,
    const float* __restrict__ Wf, const float* __restrict__ bfe,
    const float* __restrict__ Wr1, const float* __restrict__ br1,
    const float* __restrict__ Wr2, const float* __restrict__ br2,
    float* __restrict__ out, const int* __restrict__ nfix, const int* __restrict__ fixlist)
{
  int nf = *nfix; if (nf > FIXCAP) nf = FIXCAP;
  if ((int)blockIdx.x >= nf) return;
  const int tok = fixlist[blockIdx.x];
  const int tid = threadIdx.x;
  __shared__ float xf[DIN];
  __shared__ float hr[DRTR];
  if (tid < DMODEL) xf[tid] = hidden[(size_t)tok*DMODEL + tid];
  if (tid < DFEAT){
    float acc = bfe[tid];
    #pragma unroll
    for (int f=0; f<NFEAT; f++) acc += feat[(size_t)tok*NFEAT + f] * Wf[f*DFEAT + tid];
    xf[DMODEL + tid] = acc;
  }
  __syncthreads();
  {
    float acc = br1[tid];
    for (int i=0;i<DIN;i++) acc += xf[i] * Wr1[(size_t)i*DRTR + tid];
    hr[tid] = gelu_tanh(acc);
  }
  __syncthreads();
  if (tid < NE){
    float acc = br2[tid];
    for (int i=0;i<DRTR;i++) acc += hr[i] * Wr2[i*NE + tid];
    out[OUT_LOGITS + (size_t)tok*NE + tid] = acc;
  }
}

// ---- gate the flagged tokens from final (exact) logits ----
__global__ void k_gatefix(float* __restrict__ out,
                          int* __restrict__ cnts, unsigned* __restrict__ lists,
                          float* __restrict__ topw,
                          const int* __restrict__ nfix, const int* __restrict__ fixlist)
{
  int nf = *nfix; if (nf > FIXCAP) nf = FIXCAP;
  int i = threadIdx.x;
  if (i >= nf) return;
  int tok = fixlist[i];
  float v1=-3.4e38f, v2=-3.4e38f; int i1=-1, i2=-1;
  #pragma unroll
  for (int e=0;e<NE;e++){
    float v = out[OUT_LOGITS + (size_t)tok*NE + e];
    if (v > v1){ v2=v1; i2=i1; v1=v; i1=e; }
    else if (v > v2){ v2=v; i2=e; }
  }
  float d   = expf(v2 - v1);
  float inv = 1.0f/(1.0f + d);
  float w1 = inv, w2 = d*inv;
  #pragma unroll
  for (int e=0;e<NE;e++){
    float gv = (e==i1) ? w1 : ((e==i2) ? w2 : 0.f);
    out[OUT_GATEW + (size_t)tok*NE + e] = gv;
  }
  int p1 = atomicAdd(&cnts[i1], 1);
  lists[i1*N_TOK + p1] = (unsigned)(tok<<1);
  int p2 = atomicAdd(&cnts[i2], 1);
  lists[i2*N_TOK + p2] = (unsigned)((tok<<1) | 1);
  topw[tok*2]   = w1;
  topw[tok*2+1] = w2;
}

// ---- expert: TE=32, 8 waves; fragment-linear LDS; UNPINNED expert->XCD ----
// blockIdx = e*256 + tile: each expert's tiles round-robin all 8 XCDs, so
// weight reads spread across all L2s (aggregate BW) instead of one XCD slice.
#define XFL  10240
#define HFL  16384
__global__ __launch_bounds__(512) void k_expert(
    const float* __restrict__ hidden, const float* __restrict__ feat,
    const float* __restrict__ Wf, const float* __restrict__ bfe,
    const int* __restrict__ cnts, const unsigned* __restrict__ lists,
    const float* __restrict__ topw,
    const unsigned short* __restrict__ W1h, const unsigned short* __restrict__ W1l,
    const unsigned short* __restrict__ W2h, const unsigned short* __restrict__ W2l,
    const float* __restrict__ be1, const float* __restrict__ be2,
    float* __restrict__ out)
{
  __shared__ unsigned short sm[32768];   // 65536 B union: x frags -> he frags
  __shared__ int   tok_lds[TE];
  __shared__ float w_lds[TE];

  const int e    = blockIdx.x >> 8;     // expert-major: tiles spread over XCDs
  const int tile = blockIdx.x & 255;
  const int cnt  = cnts[e];
  const int start = tile * TE;
  if (start >= cnt) return;
  const int ntk = min(TE, cnt - start);
  const int tid = threadIdx.x;
  const int wv = tid >> 6;      // wave 0..7
  const int l  = tid & 63;
  const int lg = l >> 4;
  const int lr = l & 15;

  const unsigned short* p1h = W1h + (size_t)e*163840;
  const unsigned short* p1l = W1l + (size_t)e*163840;

  v8s bh_a[2], bl_a[2], bh_b[2], bl_b[2];
  auto ldB1 = [&](int ks, int jh, v8s (&bh)[2], v8s (&bl)[2]){
    #pragma unroll
    for (int j=0;j<2;++j){
      size_t boff = ((size_t)(ks*32 + wv*4 + jh*2 + j)*64 + l)*8;
      bh[j] = *(const v8s*)(p1h + boff);
      bl[j] = *(const v8s*)(p1l + boff);
    }
  };
  ldB1(0,0,bh_a,bl_a);          // early: hides under staging

  if (tid < TE){
    if (tid < ntk){
      unsigned ent = lists[e*N_TOK + start + tid];
      int tok = (int)(ent >> 1);
      tok_lds[tid] = tok;
      w_lds[tid]   = topw[tok*2 + (ent & 1)];
    } else { tok_lds[tid] = -1; w_lds[tid] = 0.f; }
  }
  __syncthreads();
  // stage x split-bf16 DIRECTLY in fragment order: entry idx=(ks*2+m)*64+l
  #pragma unroll
  for (int r=0;r<3;r++){
    int idx = r*512 + tid;
    if (idx < 1280){
      int le = idx & 63; int rest = idx >> 6;
      int m = rest & 1, ks = rest >> 1;
      int t = m*16 + (le & 15);
      int kb = ks*32 + (le >> 4)*8;
      int tok = tok_lds[t];
      float v[8];
      if (tok < 0){
        #pragma unroll
        for (int i=0;i<8;i++) v[i] = 0.f;
      } else if (kb < DMODEL){
        float4 a = *(const float4*)(hidden + (size_t)tok*DMODEL + kb);
        float4 b = *(const float4*)(hidden + (size_t)tok*DMODEL + kb + 4);
        v[0]=a.x; v[1]=a.y; v[2]=a.z; v[3]=a.w;
        v[4]=b.x; v[5]=b.y; v[6]=b.z; v[7]=b.w;
      } else {
        int j0 = kb - DMODEL;
        #pragma unroll
        for (int i=0;i<8;i++){
          float acc = bfe[j0+i];
          #pragma unroll
          for (int f=0; f<NFEAT; f++) acc += feat[(size_t)tok*NFEAT + f] * Wf[f*DFEAT + j0+i];
          v[i] = acc;
        }
      }
      unsigned short hs[8], ls[8];
      #pragma unroll
      for (int i=0;i<8;i++){
        unsigned short h = f2bf(v[i]);
        hs[i]=h; ls[i]=f2bf(v[i]-bf2f(h));
      }
      *(v8s*)&sm[idx*8]       = *(v8s*)hs;
      *(v8s*)&sm[XFL + idx*8] = *(v8s*)ls;
    }
  }
  __syncthreads();

  // phase 1: he = gelu(x @ We1[e] + be1); wave owns 4 n-tiles (2+2 halves)
  v4f acc1[2][4];
  {
    v4f z = {0.f,0.f,0.f,0.f};
    #pragma unroll
    for (int m=0;m<2;m++)
      #pragma unroll
      for (int j=0;j<4;j++) acc1[m][j] = z;
    for (int ks=0; ks<10; ++ks){
      v8s ah0 = *(const v8s*)&sm[((ks*2+0)*64 + l)*8];        // lane-linear, 0-conflict
      v8s ah1 = *(const v8s*)&sm[((ks*2+1)*64 + l)*8];
      v8s al0 = *(const v8s*)&sm[XFL + ((ks*2+0)*64 + l)*8];
      v8s al1 = *(const v8s*)&sm[XFL + ((ks*2+1)*64 + l)*8];
      ldB1(ks,1,bh_b,bl_b);
      #pragma unroll
      for (int j=0;j<2;++j) MM6(acc1[0][j],acc1[1][j], ah0,ah1,al0,al1, bh_a[j],bl_a[j]);
      if (ks<9) ldB1(ks+1,0,bh_a,bl_a);
      #pragma unroll
      for (int j=0;j<2;++j) MM6(acc1[0][2+j],acc1[1][2+j], ah0,ah1,al0,al1, bh_b[j],bl_b[j]);
    }
  }
  const unsigned short* p2h = W2h + (size_t)e*131072;
  const unsigned short* p2l = W2l + (size_t)e*131072;
  v8s ch_a[2], cl_a[2], ch_b[2], cl_b[2];
  auto ldB2 = [&](int ks, v8s (&bh)[2], v8s (&bl)[2]){
    #pragma unroll
    for (int j=0;j<2;++j){
      size_t boff = ((size_t)(ks*16 + wv*2 + j)*64 + l)*8;
      bh[j] = *(const v8s*)(p2h + boff);
      bl[j] = *(const v8s*)(p2l + boff);
    }
  };
  ldB2(0, ch_a, cl_a);          // early: hides under epilogue-1
  __syncthreads();   // x frags dead -> he frags
  // epilogue 1: bias+gelu+split, write he in PHASE-2 FRAGMENT ORDER
  #pragma unroll
  for (int j=0;j<4;++j){
    int W = wv*4 + j;                 // n-tile 0..31
    int col = W*16 + lr;
    float b1 = be1[e*DH + col];
    int ks2 = W >> 1;
    int lg2 = (W*2 + (lr>>3)) & 3;
    int i   = lr & 7;
    #pragma unroll
    for (int m=0;m<2;m++)
      #pragma unroll
      for (int r=0;r<4;r++){
        float v = gelu_tanh(acc1[m][j][r] + b1);
        unsigned short h = f2bf(v);
        int dst = ((ks2*2 + m)*64 + lg2*16 + lg*4 + r)*8 + i;
        sm[dst]       = h;
        sm[HFL + dst] = f2bf(v - bf2f(h));
      }
  }
  __syncthreads();
  // phase 2: eo = he @ We2[e] + be2; wave owns 2 n-tiles
  v4f acc2[2][2];
  {
    v4f z = {0.f,0.f,0.f,0.f};
    acc2[0][0]=z; acc2[0][1]=z; acc2[1][0]=z; acc2[1][1]=z;
    for (int ks=0; ks<16; ks+=2){
      v8s ah0 = *(const v8s*)&sm[((ks*2+0)*64 + l)*8];
      v8s ah1 = *(const v8s*)&sm[((ks*2+1)*64 + l)*8];
      v8s al0 = *(const v8s*)&sm[HFL + ((ks*2+0)*64 + l)*8];
      v8s al1 = *(const v8s*)&sm[HFL + ((ks*2+1)*64 + l)*8];
      ldB2(ks+1, ch_b, cl_b);
      #pragma unroll
      for (int j=0;j<2;++j) MM6(acc2[0][j],acc2[1][j], ah0,ah1,al0,al1, ch_a[j],cl_a[j]);
      v8s dh0 = *(const v8s*)&sm[(((ks+1)*2+0)*64 + l)*8];
      v8s dh1 = *(const v8s*)&sm[(((ks+1)*2+1)*64 + l)*8];
      v8s dl0 = *(const v8s*)&sm[HFL + (((ks+1)*2+0)*64 + l)*8];
      v8s dl1 = *(const v8s*)&sm[HFL + (((ks+1)*2+1)*64 + l)*8];
      if (ks+2<16) ldB2(ks+2, ch_a, cl_a);
      #pragma unroll
      for (int j=0;j<2;++j) MM6(acc2[0][j],acc2[1][j], dh0,dh1,dl0,dl1, ch_b[j],cl_b[j]);
    }
  }
  // epilogue 2: + be2, * gate, atomicAdd into stage_delta
  #pragma unroll
  for (int j=0;j<2;++j){
    int col = (wv*2+j)*16 + lr;
    float b2 = be2[e*DMODEL + col];
    #pragma unroll
    for (int m=0;m<2;m++)
      #pragma unroll
      for (int r=0;r<4;r++){
        int row = m*16 + lg*4 + r;
        if (row < ntk){
          float w = w_lds[row];
          atomicAdd(out + (size_t)tok_lds[row]*DMODEL + col,
                    w*(acc2[m][j][r] + b2));
        }
      }
  }
}

extern "C" void kernel_launch(void* const* d_in, const int* in_sizes, int n_in,
                              void* d_out, int out_size, void* d_ws, size_t ws_size,
                              hipStream_t stream)
{
  (void)in_sizes; (void)n_in; (void)out_size; (void)ws_size;
  const float* hidden = (const float*)d_in[0];
  const float* feat   = (const float*)d_in[1];
  const float* Wf     = (const float*)d_in[2];
  const float* bfe    = (const float*)d_in[3];
  const float* Wr1    = (const float*)d_in[4];
  const float* br1    = (const float*)d_in[5];
  const float* Wr2    = (const float*)d_in[6];
  const float* br2    = (const float*)d_in[7];
  const float* We1    = (const float*)d_in[8];
  const float* be1    = (const float*)d_in[9];
  const float* We2    = (const float*)d_in[10];
  const float* be2    = (const float*)d_in[11];
  float* out = (float*)d_out;

  // ws layout (bytes): cnts@0(8i) nfix@64 fixlist@128(128i) lists@1024 topw@263168
  //   W1h@328704 W1l@2950144 W2h@5571584 W2l@7668736 Wr1h@9765888 Wr1l@9929728 (~10.1MB)
  char* ws = (char*)d_ws;
  int*      cnts    = (int*)ws;
  int*      nfix    = (int*)(ws + 64);
  int*      fixlist = (int*)(ws + 128);
  unsigned* lists   = (unsigned*)(ws + 1024);
  float*    topw    = (float*)(ws + 263168);
  unsigned short* W1h  = (unsigned short*)(ws + 328704);
  unsigned short* W1l  = (unsigned short*)(ws + 2950144);
  unsigned short* W2h  = (unsigned short*)(ws + 5571584);
  unsigned short* W2l  = (unsigned short*)(ws + 7668736);
  unsigned short* Wr1h = (unsigned short*)(ws + 9765888);
  unsigned short* Wr1l = (unsigned short*)(ws + 9929728);

  hipLaunchKernelGGL(k_prep, dim3(219), dim3(256), 0, stream,
                     We1, We2, Wr1, W1h, W1l, W2h, W2l, Wr1h, Wr1l, cnts, nfix);
  hipLaunchKernelGGL(k_rmfma, dim3(N_TOK/RTB), dim3(512), 0, stream,
                     hidden, feat, Wf, bfe, Wr1h, Wr1l, br1, Wr2, br2,
                     out, cnts, lists, topw, nfix, fixlist);
  hipLaunchKernelGGL(k_fix, dim3(FIXCAP), dim3(256), 0, stream,
                     hidden, feat, Wf, bfe, Wr1, br1, Wr2, br2, out, nfix, fixlist);
  hipLaunchKernelGGL(k_gatefix, dim3(1), dim3(FIXCAP), 0, stream,
                     out, cnts, lists, topw, nfix, fixlist);
  hipLaunchKernelGGL(k_expert, dim3(NE*256), dim3(512), 0, stream,
                     hidden, feat, Wf, bfe, cnts, lists, topw,
                     W1h, W1l, W2h, W2l, be1, be2, out);
}